// Round 1
// 193.959 us; speedup vs baseline: 1.0157x; 1.0157x over previous
//
#include <hip/hip_runtime.h>

// Problem constants
#define BSZ    8192
#define NWRD   4
#define SEQL   16
#define HDIM   128
#define NSEQ   (BSZ * NWRD)    // 32768
#define WGSEQ  32              // sequences per workgroup
#define UPB    80              // units per length-bin (80*32=2560 slots >> E=2048)
#define BINCAP (UPB * WGSEQ)   // 2560
#define NUNITS (16 * UPB)      // 1280
#define HSTRIDE 136            // ushorts per seq row (272 B = 17*16, 16B-aligned)

typedef float  f32x4  __attribute__((ext_vector_type(4)));
typedef float  f32x16 __attribute__((ext_vector_type(16)));
typedef __bf16 bf16x8 __attribute__((ext_vector_type(8)));

union AccU { f32x16 v; f32x4 q[4]; float f[16]; };

__device__ __forceinline__ unsigned short f2bf(float f) {
    unsigned int u = __builtin_bit_cast(unsigned int, f);
    return (unsigned short)((u + 0x7fff + ((u >> 16) & 1)) >> 16);  // RNE
}
__device__ __forceinline__ float sigm(float x) {
    return __builtin_amdgcn_rcpf(1.f + __builtin_amdgcn_exp2f(x * -1.44269504f));
}
__device__ __forceinline__ float tanhx(float x) {
    return 1.f - 2.f * __builtin_amdgcn_rcpf(1.f + __builtin_amdgcn_exp2f(x * 2.88539008f));
}

// ---------------------------------------------------------------------------
// Fused prep (512 blocks):
//  blocks 0..127  : P2T[v][g][j] = b_ih[n]+b_hh[n] + emb[v]·W_ih[n], n=g*128+j
//                   (f32x4-vectorized dot product)
//  blocks 128..383: WA = W_hh bf16, A-fragment order (HW-validated):
//                   WA[((tt*8+kc)*64+lane)*8+jj] = W_hh[n][k], tt=wv*4+g,
//                   n=g*128+wv*32+(lane&31), k=kc*16+(lane>>5)*8+jj
//  blocks 384..511: direct binned scatter: bin=16-len, fixed bin base b*2560,
//                   block-aggregated atomic cursor in gh[b] (memset to 0).
// ---------------------------------------------------------------------------
__global__ void prep4(const float* __restrict__ emb, const float* __restrict__ W_ih,
                      const float* __restrict__ b_ih, const float* __restrict__ b_hh,
                      const float* __restrict__ W_hh, const int* __restrict__ lengths,
                      float* __restrict__ P2T, unsigned short* __restrict__ WA,
                      int* __restrict__ perm, int* __restrict__ gh)
{
    __shared__ int lh[16], gbase[16];
    const int blk = blockIdx.x, tid = threadIdx.x;

    if (blk < 128) {
        int idx = blk * 256 + tid;                 // 32768 = v*512 + g*128 + j
        int v = idx >> 9, g = (idx >> 7) & 3, j = idx & 127;
        int n = g * 128 + j;
        const f32x4* er = (const f32x4*)(emb  + v * 128);
        const f32x4* wr = (const f32x4*)(W_ih + n * 128);
        f32x4 s4 = er[0] * wr[0];
#pragma unroll
        for (int e = 1; e < 32; ++e) s4 += er[e] * wr[e];
        P2T[idx] = s4.x + s4.y + s4.z + s4.w + b_ih[n] + b_hh[n];
    } else if (blk < 384) {
        int idx = (blk - 128) * 256 + tid;         // 65536
        int jj = idx & 7, lane = (idx >> 3) & 63, kc = (idx >> 9) & 7, tt = idx >> 12;
        int wv = tt >> 2, g = tt & 3;
        int n = g * 128 + wv * 32 + (lane & 31);
        int k = kc * 16 + (lane >> 5) * 8 + jj;
        WA[idx] = f2bf(W_hh[n * 128 + k]);
    } else {
        if (tid < 16) lh[tid] = 0;
        __syncthreads();
        int i = (blk - 384) * 256 + tid;           // 32768 sequences
        int b = 16 - lengths[i];                   // descending-length bins
        int rank = atomicAdd(&lh[b], 1);
        __syncthreads();
        if (tid < 16) gbase[tid] = atomicAdd(&gh[tid], lh[tid]);
        __syncthreads();
        perm[b * BINCAP + gbase[b] + rank] = i;
    }
}

// ---------------------------------------------------------------------------
// LSTM, transposed GEMM: gates^T = W_hh(A, regs) x h^T(B, LDS).
// Unit = 32 same-length seqs (bin b => len 16-b, uniform -> no masking).
// 4 waves split the 128 hidden cols; C/D: seq=lane&31,
// j = 32wv + (r&3) + 8(r>>2) + 4(lane>>5). Double-buffered h -> 1 barrier/step.
// v2: dead blocks exit first; t=0 peeled (h=0 -> acc=P2, no MFMA, no hbuf
// zeroing); last step peeled (no o-gate/tanh/pack/write/barrier); next-step
// P2T gather software-pipelined into the gate phase (acc quads refilled as
// they are consumed -> gather latency hidden under gate VALU, no extra regs);
// h packed via v_cvt_pk_bf16_f32.
// ---------------------------------------------------------------------------

// Gate nonlinearity + cell update for step T. WRITE: pack/write h, prefetch
// next step's P2 into the just-consumed acc quads.
#define GATE_PHASE(T, WRITE)                                                    \
    {                                                                           \
        const int wr_ = (WRITE);                                                \
        unsigned short* hw_ = hbuf[((T) + 1) & 1];                              \
        int wn_ = 0;                                                            \
        if (wr_) wn_ = words_s[lane31 * 17 + (T) + 1];                          \
        const char* pbn_ = P2c + ((size_t)wn_ << 11) + pboff;                   \
        _Pragma("unroll")                                                       \
        for (int q = 0; q < 4; ++q) {                                           \
            float hv_[4];                                                       \
            _Pragma("unroll")                                                   \
            for (int d = 0; d < 4; ++d) {                                       \
                const int r = q * 4 + d;                                        \
                float ig = sigm(acc[0].f[r]);                                   \
                float fg = sigm(acc[1].f[r]);                                   \
                float gg = tanhx(acc[2].f[r]);                                  \
                float cn = fg * cq[q][d] + ig * gg;                             \
                cq[q][d] = cn;                                                  \
                if (wr_) {                                                      \
                    float og = sigm(acc[3].f[r]);                               \
                    hv_[d] = og * tanhx(cn);                                    \
                }                                                               \
            }                                                                   \
            if (wr_) {                                                          \
                unsigned int plo_, phi_;                                        \
                asm("v_cvt_pk_bf16_f32 %0, %1, %2"                              \
                    : "=v"(plo_) : "v"(hv_[0]), "v"(hv_[1]));                   \
                asm("v_cvt_pk_bf16_f32 %0, %1, %2"                              \
                    : "=v"(phi_) : "v"(hv_[2]), "v"(hv_[3]));                   \
                unsigned long long pu_ =                                        \
                    ((unsigned long long)phi_ << 32) | plo_;                    \
                *(unsigned long long*)(hw_ + rdo + jbase + 8 * q) = pu_;        \
                /* refill consumed acc quads with next step's P2 */             \
                _Pragma("unroll")                                               \
                for (int g = 0; g < 4; ++g)                                     \
                    acc[g].q[q] = *(const f32x4*)(pbn_ + g * 512 + q * 32);     \
            }                                                                   \
        }                                                                       \
    }

// h-GEMM for step T: B fragments from hbuf[T&1], accumulate into acc (= P2).
#define MFMA_STEP(T)                                                            \
    {                                                                           \
        const unsigned short* hr_ = hbuf[(T) & 1];                              \
        bf16x8 bfv_[8];                                                         \
        _Pragma("unroll")                                                       \
        for (int kc = 0; kc < 8; ++kc)                                          \
            bfv_[kc] = *(const bf16x8*)(hr_ + rdo + kc * 16 + hl * 8);          \
        _Pragma("unroll")                                                       \
        for (int kc = 0; kc < 8; ++kc) {                                        \
            const bf16x8 bb_ = bfv_[kc];                                        \
            _Pragma("unroll")                                                   \
            for (int g = 0; g < 4; ++g)                                         \
                acc[g].v = __builtin_amdgcn_mfma_f32_32x32x16_bf16(             \
                    afr[g][kc], bb_, acc[g].v, 0, 0, 0);                        \
        }                                                                       \
    }

__global__ __launch_bounds__(256, 2) void lstm4(
    const int* __restrict__ word_ids, const int* __restrict__ perm,
    const int* __restrict__ gh, const float* __restrict__ P2T,
    const unsigned short* __restrict__ WA, float* __restrict__ c_out)
{
    __shared__ __align__(16) unsigned short hbuf[2][WGSEQ * HSTRIDE];  // 2 x 8704 B
    __shared__ int words_s[WGSEQ * 17];
    __shared__ int sid_s[WGSEQ];

    const int tid    = threadIdx.x;
    const int wv     = tid >> 6;
    const int lane   = tid & 63;
    const int lane31 = lane & 31;
    const int hl     = lane >> 5;

    const int u    = blockIdx.x;       // 0..1279, bin-major (longest first)
    const int b    = u / UPB;
    const int widx = u % UPB;
    const int cnt  = gh[b];            // bin population (uniform scalar)
    if (widx * WGSEQ >= cnt) return;   // dead block: exit before any loads
    const int ml   = 16 - b;           // uniform trip count (>=1)

    if (tid < WGSEQ) {
        int slot = widx * WGSEQ + tid;
        sid_s[tid] = (slot < cnt) ? perm[b * BINCAP + slot] : 0;
    }
    __syncthreads();
    for (int i = tid; i < WGSEQ * SEQL; i += 256)
        words_s[(i >> 4) * 17 + (i & 15)] = word_ids[sid_s[i >> 4] * SEQL + (i & 15)];
    __syncthreads();

    // A fragments: W_hh, persistent in registers (4 g-tiles x 8 kc x 4 VGPR)
    bf16x8 afr[4][8];
#pragma unroll
    for (int g = 0; g < 4; ++g)
#pragma unroll
        for (int kc = 0; kc < 8; ++kc)
            afr[g][kc] = *(const bf16x8*)(WA + (((wv * 4 + g) * 8 + kc) * 64 + lane) * 8);

    f32x4 cq[4] = {{0,0,0,0},{0,0,0,0},{0,0,0,0},{0,0,0,0}};
    const char* P2c  = (const char*)P2T;
    const int pboff  = wv * 128 + hl * 16;      // byte offset within a P row
    const int rdo    = lane31 * HSTRIDE;        // ushort offset of own seq row
    const int jbase  = wv * 32 + 4 * hl;        // first j of q-group 0

    // prologue: acc = P2 of word 0 (t=0 has h=0 -> gates are P2 only)
    AccU acc[4];
    {
        const int w0 = words_s[lane31 * 17];
        const char* pb = P2c + ((size_t)w0 << 11) + pboff;
#pragma unroll
        for (int g = 0; g < 4; ++g)
#pragma unroll
            for (int q = 0; q < 4; ++q)
                acc[g].q[q] = *(const f32x4*)(pb + g * 512 + q * 32);
    }

    GATE_PHASE(0, ml > 1);             // t=0: no MFMA, no prior h
    if (ml > 1) {
        __syncthreads();
#pragma unroll 1
        for (int t = 1; t < ml - 1; ++t) {
            MFMA_STEP(t);
            GATE_PHASE(t, 1);
            __syncthreads();
        }
        MFMA_STEP(ml - 1);
        GATE_PHASE(ml - 1, 0);         // last step: c only, no h/pack/barrier
    }

    // final cell state -> original seq order (dwordx4 stores)
    if (widx * WGSEQ + lane31 < cnt) {
        const int sid = sid_s[lane31];
#pragma unroll
        for (int q = 0; q < 4; ++q)
            *(f32x4*)(c_out + sid * HDIM + jbase + 8 * q) = cq[q];
    }
}

// ---------------------------------------------------------------------------
// Per-batch epilogue: gram -> cosine -> conv1 -> conv2 -> scorer -> sigmoid.
// ---------------------------------------------------------------------------
__global__ __launch_bounds__(256) void epilogue(
    const float* __restrict__ c_ws,
    const float* __restrict__ conv1_w, const float* __restrict__ conv1_b,
    const float* __restrict__ conv2_w, const float* __restrict__ conv2_b,
    const float* __restrict__ scorer_w, const float* __restrict__ scorer_b,
    float* __restrict__ out)
{
    __shared__ __align__(16) float reps[8 * NWRD * HDIM];   // 16KB
    __shared__ float gram_s[8 * 16];

    const int tid = threadIdx.x;
    const int b0  = blockIdx.x * 8;

    for (int i = tid; i < 8 * NWRD * HDIM; i += 256)
        reps[i] = c_ws[b0 * NWRD * HDIM + i];
    __syncthreads();

    const int bt  = tid >> 5;   // 0..7
    const int sub = tid & 31;

    float dval = 0.f;
    if (sub < 16) {
        int i = sub >> 2, j = sub & 3;
        const f32x4* ci = (const f32x4*)(reps + (bt * 4 + i) * HDIM);
        const f32x4* cj = (const f32x4*)(reps + (bt * 4 + j) * HDIM);
        f32x4 s4 = {0.f, 0.f, 0.f, 0.f};
        for (int k = 0; k < HDIM / 4; ++k) s4 += ci[k] * cj[k];
        dval = s4.x + s4.y + s4.z + s4.w;
        gram_s[bt * 16 + sub] = dval;
    }
    __syncthreads();
    float cosv = 0.f;
    if (sub < 16) {
        int i = sub >> 2, j = sub & 3;
        float di = gram_s[bt * 16 + i * 4 + i];
        float dj = gram_s[bt * 16 + j * 4 + j];
        cosv = __fdividef(dval, sqrtf(di * dj));
    }
    __syncthreads();
    if (sub < 16) gram_s[bt * 16 + sub] = cosv;
    __syncthreads();

    if (sub == 0) {
        float img[4][4];
#pragma unroll
        for (int i = 0; i < 4; ++i)
#pragma unroll
            for (int j = 0; j < 4; ++j) img[i][j] = gram_s[bt * 16 + i * 4 + j];

        float o1[4][3][3];
#pragma unroll
        for (int ch = 0; ch < 4; ++ch) {
            float w00 = conv1_w[ch*4+0], w01 = conv1_w[ch*4+1];
            float w10 = conv1_w[ch*4+2], w11 = conv1_w[ch*4+3];
            float bb  = conv1_b[ch];
#pragma unroll
            for (int y = 0; y < 3; ++y)
#pragma unroll
                for (int x = 0; x < 3; ++x) {
                    float s = bb + w00*img[y][x]   + w01*img[y][x+1]
                                 + w10*img[y+1][x] + w11*img[y+1][x+1];
                    o1[ch][y][x] = s > 0.f ? s : 0.f;
                }
        }
        float sc = scorer_b[0];
#pragma unroll
        for (int oc = 0; oc < 8; ++oc) {
            float bb = conv2_b[oc];
#pragma unroll
            for (int y = 0; y < 2; ++y)
#pragma unroll
                for (int x = 0; x < 2; ++x) {
                    float s = bb;
#pragma unroll
                    for (int ic = 0; ic < 4; ++ic) {
                        const float* w = conv2_w + oc * 16 + ic * 4;
                        s += w[0]*o1[ic][y][x]   + w[1]*o1[ic][y][x+1]
                           + w[2]*o1[ic][y+1][x] + w[3]*o1[ic][y+1][x+1];
                    }
                    float rl = s > 0.f ? s : 0.f;
                    sc += rl * scorer_w[oc * 4 + y * 2 + x];
                }
        }
        out[blockIdx.x * 8 + bt] = sigm(sc);
    }
}

extern "C" void kernel_launch(void* const* d_in, const int* in_sizes, int n_in,
                              void* d_out, int out_size, void* d_ws, size_t ws_size,
                              hipStream_t stream)
{
    const int*   word_ids = (const int*)d_in[0];
    const int*   lengths  = (const int*)d_in[1];
    const float* emb      = (const float*)d_in[2];
    const float* W_ih     = (const float*)d_in[3];
    const float* W_hh     = (const float*)d_in[4];
    const float* b_ih     = (const float*)d_in[5];
    const float* b_hh     = (const float*)d_in[6];
    const float* conv1_w  = (const float*)d_in[7];
    const float* conv1_b  = (const float*)d_in[8];
    const float* conv2_w  = (const float*)d_in[9];
    const float* conv2_b  = (const float*)d_in[10];
    const float* scorer_w = (const float*)d_in[11];
    const float* scorer_b = (const float*)d_in[12];
    float* out = (float*)d_out;

    // workspace layout
    char* ws = (char*)d_ws;
    float*          P2T  = (float*)(ws + 0);                  // 128 KB
    unsigned short* WA   = (unsigned short*)(ws + (128<<10)); // 128 KB
    int*            perm = (int*)(ws + (256<<10));            // 16*2560*4 = 160 KB
    int*            gh   = (int*)(ws + (416<<10));            // 64 B bin cursors
    float*          c_ws = (float*)(ws + (512<<10));          // 16 MB

    hipMemsetAsync(gh, 0, 16 * sizeof(int), stream);
    prep4   <<<512,   256, 0, stream>>>(emb, W_ih, b_ih, b_hh, W_hh, lengths,
                                        P2T, WA, perm, gh);
    lstm4   <<<NUNITS, 256, 0, stream>>>(word_ids, perm, gh, P2T, WA, c_ws);
    epilogue<<<BSZ / 8, 256, 0, stream>>>(c_ws, conv1_w, conv1_b, conv2_w, conv2_b,
                                          scorer_w, scorer_b, out);
}

// Round 2
// 184.660 us; speedup vs baseline: 1.0669x; 1.0504x over previous
//
#include <hip/hip_runtime.h>

// Problem constants
#define BSZ    8192
#define NWRD   4
#define SEQL   16
#define HDIM   128
#define NSEQ   (BSZ * NWRD)    // 32768
#define WGSEQ  32              // sequences per workgroup
#define UPB    80              // units per length-bin (80*32=2560 slots >> E=2048)
#define BINCAP (UPB * WGSEQ)   // 2560
#define NUNITS (16 * UPB)      // 1280
#define HSTRIDE 136            // ushorts per seq row (272 B = 17*16, 16B-aligned)

#define AS1 __attribute__((address_space(1)))
#define AS3 __attribute__((address_space(3)))

typedef float  f32x4  __attribute__((ext_vector_type(4)));
typedef float  f32x16 __attribute__((ext_vector_type(16)));
typedef __bf16 bf16x8 __attribute__((ext_vector_type(8)));

union AccU { f32x16 v; f32x4 q[4]; float f[16]; };

__device__ __forceinline__ unsigned short f2bf(float f) {
    unsigned int u = __builtin_bit_cast(unsigned int, f);
    return (unsigned short)((u + 0x7fff + ((u >> 16) & 1)) >> 16);  // RNE
}
__device__ __forceinline__ float sigm(float x) {
    return __builtin_amdgcn_rcpf(1.f + __builtin_amdgcn_exp2f(x * -1.44269504f));
}
__device__ __forceinline__ float tanhx(float x) {
    return 1.f - 2.f * __builtin_amdgcn_rcpf(1.f + __builtin_amdgcn_exp2f(x * 2.88539008f));
}

// ---------------------------------------------------------------------------
// Fused prep (512 blocks): P2T rows, WA (W_hh bf16 A-frags), binned perm.
// ---------------------------------------------------------------------------
__global__ void prep4(const float* __restrict__ emb, const float* __restrict__ W_ih,
                      const float* __restrict__ b_ih, const float* __restrict__ b_hh,
                      const float* __restrict__ W_hh, const int* __restrict__ lengths,
                      float* __restrict__ P2T, unsigned short* __restrict__ WA,
                      int* __restrict__ perm, int* __restrict__ gh)
{
    __shared__ int lh[16], gbase[16];
    const int blk = blockIdx.x, tid = threadIdx.x;

    if (blk < 128) {
        int idx = blk * 256 + tid;                 // 32768 = v*512 + g*128 + j
        int v = idx >> 9, g = (idx >> 7) & 3, j = idx & 127;
        int n = g * 128 + j;
        const f32x4* er = (const f32x4*)(emb  + v * 128);
        const f32x4* wr = (const f32x4*)(W_ih + n * 128);
        f32x4 s4 = er[0] * wr[0];
#pragma unroll
        for (int e = 1; e < 32; ++e) s4 += er[e] * wr[e];
        P2T[idx] = s4.x + s4.y + s4.z + s4.w + b_ih[n] + b_hh[n];
    } else if (blk < 384) {
        int idx = (blk - 128) * 256 + tid;         // 65536
        int jj = idx & 7, lane = (idx >> 3) & 63, kc = (idx >> 9) & 7, tt = idx >> 12;
        int wv = tt >> 2, g = tt & 3;
        int n = g * 128 + wv * 32 + (lane & 31);
        int k = kc * 16 + (lane >> 5) * 8 + jj;
        WA[idx] = f2bf(W_hh[n * 128 + k]);
    } else {
        if (tid < 16) lh[tid] = 0;
        __syncthreads();
        int i = (blk - 384) * 256 + tid;           // 32768 sequences
        int b = 16 - lengths[i];                   // descending-length bins
        int rank = atomicAdd(&lh[b], 1);
        __syncthreads();
        if (tid < 16) gbase[tid] = atomicAdd(&gh[tid], lh[tid]);
        __syncthreads();
        perm[b * BINCAP + gbase[b] + rank] = i;
    }
}

// ---------------------------------------------------------------------------
// LSTM, transposed GEMM: gates^T = W_hh(A, regs) x h^T(B, LDS).
// v3: per-step divergent P2T gather (16 loads x 32 cachelines each = TA-bound)
// replaced by coalesced LDS staging: 16 global_load_lds dwordx4 per wave
// stream the 32 needed 2KB P-rows into pbuf; acc-init becomes ds_read_b128.
// XOR swizzle ((s&7)<<4, 16B granular) applied to BOTH the pre-swizzled
// global source and the LDS read -> even 8-lanes/quad distribution
// (conflict-free minimum for b128). Single-buffered pbuf + hbuf (74.8 KB,
// 2 blocks/CU), 2 barriers/step:
//   [reads of pbuf/hbuf] A [stage P(t+1) | MFMA | gates -> h-write] B
// ---------------------------------------------------------------------------

#define LOAD_W(T)                                                               \
    { _Pragma("unroll")                                                         \
      for (int r_ = 0; r_ < 8; ++r_)                                            \
          wreg[r_] = words_s[(wv * 8 + r_) * 17 + (T)]; }

// 16 coalesced global->LDS stages (8 rows x 2KB per wave), sources pre-swizzled
#define STAGE_P()                                                               \
    { _Pragma("unroll")                                                         \
      for (int r_ = 0; r_ < 8; ++r_) {                                          \
          const int s_ = wv * 8 + r_;                                           \
          const unsigned xv_ = (unsigned)((s_ & 7) << 4);                       \
          const char* sb_ = (const char*)(P2T + ((size_t)wreg[r_] << 9));       \
          float* db_ = pbuf + (s_ << 9);                                        \
          __builtin_amdgcn_global_load_lds(                                     \
              (const AS1 unsigned int*)(sb_ + ((unsigned)(lane << 4) ^ xv_)),   \
              (AS3 unsigned int*)db_, 16, 0, 0);                                \
          __builtin_amdgcn_global_load_lds(                                     \
              (const AS1 unsigned int*)(sb_ + ((1024u + (unsigned)(lane << 4)) ^ xv_)), \
              (AS3 unsigned int*)(db_ + 256), 16, 0, 0);                        \
      } }

// acc init: own seq's P row from LDS (swizzled), 16 x ds_read_b128
#define LOAD_ACC()                                                              \
    { const char* pr_ = (const char*)pbuf + (lane31 << 11);                     \
      const unsigned xv_ = (unsigned)((lane31 & 7) << 4);                       \
      _Pragma("unroll")                                                         \
      for (int g = 0; g < 4; ++g)                                               \
          _Pragma("unroll")                                                     \
          for (int q = 0; q < 4; ++q)                                           \
              acc[g].q[q] = *(const f32x4*)(pr_ +                               \
                  (((unsigned)(g * 512 + q * 32 + pboff)) ^ xv_)); }

#define LOAD_B()                                                                \
    { _Pragma("unroll")                                                         \
      for (int kc = 0; kc < 8; ++kc)                                            \
          bfv[kc] = *(const bf16x8*)(hbuf + rdo + kc * 16 + hl * 8); }

#define MFMA_ALL()                                                              \
    { _Pragma("unroll")                                                         \
      for (int kc = 0; kc < 8; ++kc) {                                          \
          const bf16x8 bb_ = bfv[kc];                                           \
          _Pragma("unroll")                                                     \
          for (int g = 0; g < 4; ++g)                                           \
              acc[g].v = __builtin_amdgcn_mfma_f32_32x32x16_bf16(               \
                  afr[g][kc], bb_, acc[g].v, 0, 0, 0);                          \
      } }

// Gate nonlinearity + cell update. WRITE: pack h (v_cvt_pk_bf16_f32) + ds_write.
#define GATE_PHASE(WRITE)                                                       \
    {                                                                           \
        const int wr_ = (WRITE);                                                \
        _Pragma("unroll")                                                       \
        for (int q = 0; q < 4; ++q) {                                           \
            float hv_[4];                                                       \
            _Pragma("unroll")                                                   \
            for (int d = 0; d < 4; ++d) {                                       \
                const int r = q * 4 + d;                                        \
                float ig = sigm(acc[0].f[r]);                                   \
                float fg = sigm(acc[1].f[r]);                                   \
                float gg = tanhx(acc[2].f[r]);                                  \
                float cn = fg * cq[q][d] + ig * gg;                             \
                cq[q][d] = cn;                                                  \
                if (wr_) {                                                      \
                    float og = sigm(acc[3].f[r]);                               \
                    hv_[d] = og * tanhx(cn);                                    \
                }                                                               \
            }                                                                   \
            if (wr_) {                                                          \
                unsigned int plo_, phi_;                                        \
                asm("v_cvt_pk_bf16_f32 %0, %1, %2"                              \
                    : "=v"(plo_) : "v"(hv_[0]), "v"(hv_[1]));                   \
                asm("v_cvt_pk_bf16_f32 %0, %1, %2"                              \
                    : "=v"(phi_) : "v"(hv_[2]), "v"(hv_[3]));                   \
                unsigned long long pu_ =                                        \
                    ((unsigned long long)phi_ << 32) | plo_;                    \
                *(unsigned long long*)(hbuf + rdo + jbase + 8 * q) = pu_;       \
            }                                                                   \
        }                                                                       \
    }

__global__ __launch_bounds__(256, 2) void lstm4(
    const int* __restrict__ word_ids, const int* __restrict__ perm,
    const int* __restrict__ gh, const float* __restrict__ P2T,
    const unsigned short* __restrict__ WA, float* __restrict__ c_out)
{
    __shared__ __align__(16) float pbuf[WGSEQ * 512];               // 64 KB
    __shared__ __align__(16) unsigned short hbuf[WGSEQ * HSTRIDE];  // 8704 B
    __shared__ int words_s[WGSEQ * 17];                             // 2176 B
    __shared__ int sid_s[WGSEQ];                                    // 128 B

    const int tid    = threadIdx.x;
    const int wv     = tid >> 6;
    const int lane   = tid & 63;
    const int lane31 = lane & 31;
    const int hl     = lane >> 5;

    const int u    = blockIdx.x;       // 0..1279, bin-major (longest first)
    const int b    = u / UPB;
    const int widx = u % UPB;
    const int cnt  = gh[b];            // bin population (uniform scalar)
    if (widx * WGSEQ >= cnt) return;   // dead block: exit before any loads
    const int ml   = 16 - b;           // uniform trip count (>=1)

    // A fragments: W_hh, persistent in registers (independent of LDS; overlap)
    bf16x8 afr[4][8];
#pragma unroll
    for (int g = 0; g < 4; ++g)
#pragma unroll
        for (int kc = 0; kc < 8; ++kc)
            afr[g][kc] = *(const bf16x8*)(WA + (((wv * 4 + g) * 8 + kc) * 64 + lane) * 8);

    if (tid < WGSEQ) {
        int slot = widx * WGSEQ + tid;
        sid_s[tid] = (slot < cnt) ? perm[b * BINCAP + slot] : 0;
    }
    __syncthreads();
    for (int i = tid; i < WGSEQ * SEQL; i += 256)
        words_s[(i >> 4) * 17 + (i & 15)] = word_ids[sid_s[i >> 4] * SEQL + (i & 15)];
    __syncthreads();

    f32x4 cq[4] = {{0,0,0,0},{0,0,0,0},{0,0,0,0},{0,0,0,0}};
    const int pboff = wv * 128 + hl * 16;      // byte offset within a P row
    const int rdo   = lane31 * HSTRIDE;        // ushort offset of own seq row
    const int jbase = wv * 32 + 4 * hl;        // first j of q-group 0
    int wreg[8];

    // prologue: stage + consume P(0); t=0 has h=0 -> gates are P2 only
    LOAD_W(0);
    STAGE_P();
    __syncthreads();                   // P(0) staged (vmcnt drained by barrier)

    AccU acc[4];
    LOAD_ACC();
    if (ml > 1) {
        __syncthreads();               // [A] pbuf reads done -> free
        LOAD_W(1);
        STAGE_P();                     // stage P(1) under t=0 gates
    }
    GATE_PHASE(ml > 1);                // t=0 (writes h(1) if needed)

    if (ml > 1) {
        __syncthreads();               // [B] P(1) + h(1) ready
        bf16x8 bfv[8];
#pragma unroll 1
        for (int t = 1; t < ml - 1; ++t) {
            LOAD_B();
            LOAD_ACC();
            LOAD_W(t + 1);
            __syncthreads();           // [A] pbuf/hbuf reads done
            STAGE_P();                 // stage P(t+1) under MFMA+gates
            MFMA_ALL();
            GATE_PHASE(1);
            __syncthreads();           // [B] stage + h-writes drained
        }
        // final step: no stage, no h-write, no barrier
        LOAD_B();
        LOAD_ACC();
        MFMA_ALL();
        GATE_PHASE(0);
    }

    // final cell state -> original seq order (dwordx4 stores)
    if (widx * WGSEQ + lane31 < cnt) {
        const int sid = sid_s[lane31];
#pragma unroll
        for (int q = 0; q < 4; ++q)
            *(f32x4*)(c_out + sid * HDIM + jbase + 8 * q) = cq[q];
    }
}

// ---------------------------------------------------------------------------
// Per-batch epilogue: gram -> cosine -> conv1 -> conv2 -> scorer -> sigmoid.
// ---------------------------------------------------------------------------
__global__ __launch_bounds__(256) void epilogue(
    const float* __restrict__ c_ws,
    const float* __restrict__ conv1_w, const float* __restrict__ conv1_b,
    const float* __restrict__ conv2_w, const float* __restrict__ conv2_b,
    const float* __restrict__ scorer_w, const float* __restrict__ scorer_b,
    float* __restrict__ out)
{
    __shared__ __align__(16) float reps[8 * NWRD * HDIM];   // 16KB
    __shared__ float gram_s[8 * 16];

    const int tid = threadIdx.x;
    const int b0  = blockIdx.x * 8;

    for (int i = tid; i < 8 * NWRD * HDIM; i += 256)
        reps[i] = c_ws[b0 * NWRD * HDIM + i];
    __syncthreads();

    const int bt  = tid >> 5;   // 0..7
    const int sub = tid & 31;

    float dval = 0.f;
    if (sub < 16) {
        int i = sub >> 2, j = sub & 3;
        const f32x4* ci = (const f32x4*)(reps + (bt * 4 + i) * HDIM);
        const f32x4* cj = (const f32x4*)(reps + (bt * 4 + j) * HDIM);
        f32x4 s4 = {0.f, 0.f, 0.f, 0.f};
        for (int k = 0; k < HDIM / 4; ++k) s4 += ci[k] * cj[k];
        dval = s4.x + s4.y + s4.z + s4.w;
        gram_s[bt * 16 + sub] = dval;
    }
    __syncthreads();
    float cosv = 0.f;
    if (sub < 16) {
        int i = sub >> 2, j = sub & 3;
        float di = gram_s[bt * 16 + i * 4 + i];
        float dj = gram_s[bt * 16 + j * 4 + j];
        cosv = __fdividef(dval, sqrtf(di * dj));
    }
    __syncthreads();
    if (sub < 16) gram_s[bt * 16 + sub] = cosv;
    __syncthreads();

    if (sub == 0) {
        float img[4][4];
#pragma unroll
        for (int i = 0; i < 4; ++i)
#pragma unroll
            for (int j = 0; j < 4; ++j) img[i][j] = gram_s[bt * 16 + i * 4 + j];

        float o1[4][3][3];
#pragma unroll
        for (int ch = 0; ch < 4; ++ch) {
            float w00 = conv1_w[ch*4+0], w01 = conv1_w[ch*4+1];
            float w10 = conv1_w[ch*4+2], w11 = conv1_w[ch*4+3];
            float bb  = conv1_b[ch];
#pragma unroll
            for (int y = 0; y < 3; ++y)
#pragma unroll
                for (int x = 0; x < 3; ++x) {
                    float s = bb + w00*img[y][x]   + w01*img[y][x+1]
                                 + w10*img[y+1][x] + w11*img[y+1][x+1];
                    o1[ch][y][x] = s > 0.f ? s : 0.f;
                }
        }
        float sc = scorer_b[0];
#pragma unroll
        for (int oc = 0; oc < 8; ++oc) {
            float bb = conv2_b[oc];
#pragma unroll
            for (int y = 0; y < 2; ++y)
#pragma unroll
                for (int x = 0; x < 2; ++x) {
                    float s = bb;
#pragma unroll
                    for (int ic = 0; ic < 4; ++ic) {
                        const float* w = conv2_w + oc * 16 + ic * 4;
                        s += w[0]*o1[ic][y][x]   + w[1]*o1[ic][y][x+1]
                           + w[2]*o1[ic][y+1][x] + w[3]*o1[ic][y+1][x+1];
                    }
                    float rl = s > 0.f ? s : 0.f;
                    sc += rl * scorer_w[oc * 4 + y * 2 + x];
                }
        }
        out[blockIdx.x * 8 + bt] = sigm(sc);
    }
}

extern "C" void kernel_launch(void* const* d_in, const int* in_sizes, int n_in,
                              void* d_out, int out_size, void* d_ws, size_t ws_size,
                              hipStream_t stream)
{
    const int*   word_ids = (const int*)d_in[0];
    const int*   lengths  = (const int*)d_in[1];
    const float* emb      = (const float*)d_in[2];
    const float* W_ih     = (const float*)d_in[3];
    const float* W_hh     = (const float*)d_in[4];
    const float* b_ih     = (const float*)d_in[5];
    const float* b_hh     = (const float*)d_in[6];
    const float* conv1_w  = (const float*)d_in[7];
    const float* conv1_b  = (const float*)d_in[8];
    const float* conv2_w  = (const float*)d_in[9];
    const float* conv2_b  = (const float*)d_in[10];
    const float* scorer_w = (const float*)d_in[11];
    const float* scorer_b = (const float*)d_in[12];
    float* out = (float*)d_out;

    // workspace layout
    char* ws = (char*)d_ws;
    float*          P2T  = (float*)(ws + 0);                  // 128 KB
    unsigned short* WA   = (unsigned short*)(ws + (128<<10)); // 128 KB
    int*            perm = (int*)(ws + (256<<10));            // 16*2560*4 = 160 KB
    int*            gh   = (int*)(ws + (416<<10));            // 64 B bin cursors
    float*          c_ws = (float*)(ws + (512<<10));          // 16 MB

    hipMemsetAsync(gh, 0, 16 * sizeof(int), stream);
    prep4   <<<512,   256, 0, stream>>>(emb, W_ih, b_ih, b_hh, W_hh, lengths,
                                        P2T, WA, perm, gh);
    lstm4   <<<NUNITS, 256, 0, stream>>>(word_ids, perm, gh, P2T, WA, c_ws);
    epilogue<<<BSZ / 8, 256, 0, stream>>>(c_ws, conv1_w, conv1_b, conv2_w, conv2_b,
                                          scorer_w, scorer_b, out);
}

// Round 3
// 172.312 us; speedup vs baseline: 1.1434x; 1.0717x over previous
//
#include <hip/hip_runtime.h>

// Problem constants
#define BSZ    8192
#define NWRD   4
#define SEQL   16
#define HDIM   128
#define VOCAB  64
#define NSEQ   (BSZ * NWRD)    // 32768
#define WGSEQ  32              // sequences per workgroup
#define UPB    80              // units per length-bin (80*32=2560 slots)
#define BINCAP (UPB * WGSEQ)   // 2560
#define NUNITS (16 * UPB)      // 1280

#define AS1 __attribute__((address_space(1)))
#define AS3 __attribute__((address_space(3)))

typedef float    f32x4  __attribute__((ext_vector_type(4)));
typedef float    f32x16 __attribute__((ext_vector_type(16)));
typedef __bf16   bf16x8 __attribute__((ext_vector_type(8)));
typedef _Float16 f16x8  __attribute__((ext_vector_type(8)));
typedef int      i32x4  __attribute__((ext_vector_type(4)));

union AccU { f32x16 v; f32x4 q[4]; float f[16]; };

__device__ __forceinline__ unsigned short f2bf(float f) {
    unsigned int u = __builtin_bit_cast(unsigned int, f);
    return (unsigned short)((u + 0x7fff + ((u >> 16) & 1)) >> 16);  // RNE
}
__device__ __forceinline__ float sigm(float x) {
    return __builtin_amdgcn_rcpf(1.f + __builtin_amdgcn_exp2f(x * -1.44269504f));
}

// ---------------------------------------------------------------------------
// Fused prep (512 blocks):
//  blocks 0..127  : P table in f16, LSTM-fragment layout + per-row chunk
//                   permutation (chunk ^= w&7) for LDS bank spread.
//                   half index F = v*512 + ((cc ^ (v&7))<<3) + (q&1)*4 + d,
//                   cc = g*16 + wv*4 + hl*2 + (q>>1), j = wv*32+4hl+8q+d.
//  blocks 128..383: WA = W_hh bf16, A-fragment order (HW-validated).
//  blocks 384..511: binned scatter: bin=16-len, cursor in gh[b].
// ---------------------------------------------------------------------------
__global__ void prep4(const float* __restrict__ emb, const float* __restrict__ W_ih,
                      const float* __restrict__ b_ih, const float* __restrict__ b_hh,
                      const float* __restrict__ W_hh, const int* __restrict__ lengths,
                      unsigned short* __restrict__ P2H, unsigned short* __restrict__ WA,
                      int* __restrict__ perm, int* __restrict__ gh)
{
    __shared__ int lh[16], gbase[16];
    const int blk = blockIdx.x, tid = threadIdx.x;

    if (blk < 128) {
        int idx = blk * 256 + tid;                 // 32768 = v*512 + g*128 + j
        int v = idx >> 9, g = (idx >> 7) & 3, j = idx & 127;
        int n = g * 128 + j;
        const f32x4* er = (const f32x4*)(emb  + v * 128);
        const f32x4* wr = (const f32x4*)(W_ih + n * 128);
        f32x4 s4 = er[0] * wr[0];
#pragma unroll
        for (int e = 1; e < 32; ++e) s4 += er[e] * wr[e];
        float s = s4.x + s4.y + s4.z + s4.w + b_ih[n] + b_hh[n];
        // scatter into LSTM fragment layout (f16)
        int wv = j >> 5, jr = j & 31;
        int d = jr & 3, hl = (jr >> 2) & 1, q = jr >> 3;
        int cc = g * 16 + wv * 4 + hl * 2 + (q >> 1);
        int F  = v * 512 + ((cc ^ (v & 7)) << 3) + (q & 1) * 4 + d;
        P2H[F] = __builtin_bit_cast(unsigned short, (_Float16)s);
    } else if (blk < 384) {
        int idx = (blk - 128) * 256 + tid;         // 65536
        int jj = idx & 7, lane = (idx >> 3) & 63, kc = (idx >> 9) & 7, tt = idx >> 12;
        int wv = tt >> 2, g = tt & 3;
        int n = g * 128 + wv * 32 + (lane & 31);
        int k = kc * 16 + (lane >> 5) * 8 + jj;
        WA[idx] = f2bf(W_hh[n * 128 + k]);
    } else {
        if (tid < 16) lh[tid] = 0;
        __syncthreads();
        int i = (blk - 384) * 256 + tid;           // 32768 sequences
        int b = 16 - lengths[i];                   // descending-length bins
        int rank = atomicAdd(&lh[b], 1);
        __syncthreads();
        if (tid < 16) gbase[tid] = atomicAdd(&gh[tid], lh[tid]);
        __syncthreads();
        perm[b * BINCAP + gbase[b] + rank] = i;
    }
}

// ---------------------------------------------------------------------------
// LSTM, transposed GEMM: gates^T = W_hh(A, regs) x h^T(B, LDS).
// v4: V=64 -> whole P table (f16, 64KB) is LDS-resident per block, loaded
// once via global_load_lds; per-step acc init = 8 ds_read_b128 from the
// static table (chunk^w&7 bank spread). No per-step staging, no vmcnt
// drain, ONE barrier/step (h double-buffer, XOR-swizzled 256B rows).
// Words held in a packed 64-bit shift register (no LDS, no runtime idx).
// Gate math: shared-rcp forms, 10 -> 8 transcendentals/elem (exact).
// LDS = 64KB table + 16KB hbuf = exactly 80KB -> 2 blocks/CU.
// ---------------------------------------------------------------------------
__global__ __launch_bounds__(256, 2) void lstm4(
    const int* __restrict__ word_ids, const int* __restrict__ perm,
    const int* __restrict__ gh, const unsigned short* __restrict__ P2H,
    const unsigned short* __restrict__ WA, float* __restrict__ c_out)
{
    __shared__ __align__(16) unsigned short ptab[VOCAB * 512];     // 64 KB
    __shared__ __align__(16) unsigned short hbuf[2][WGSEQ * 128];  // 16 KB

    const int tid    = threadIdx.x;
    const int wv     = tid >> 6;
    const int lane   = tid & 63;
    const int lane31 = lane & 31;
    const int hl     = lane >> 5;

    const int u    = blockIdx.x;       // 0..1279, bin-major (longest first)
    const int b    = u / UPB;
    const int widx = u % UPB;
    const int cnt  = gh[b];            // bin population (uniform scalar)
    if (widx * WGSEQ >= cnt) return;   // dead block: exit before any loads
    const int ml   = 16 - b;           // uniform trip count (>=1)

    // stage the whole P table into LDS (linear copy, async)
    {
        const char* src = (const char*)P2H;
        char*       dst = (char*)ptab;
#pragma unroll
        for (int r = 0; r < 16; ++r) {
            const int off = r * 4096 + wv * 1024;   // wave-uniform dest base
            __builtin_amdgcn_global_load_lds(
                (const AS1 unsigned int*)(src + off + lane * 16),
                (AS3 unsigned int*)(dst + off), 16, 0, 0);
        }
    }

    // A fragments: W_hh, persistent in registers
    bf16x8 afr[4][8];
#pragma unroll
    for (int g = 0; g < 4; ++g)
#pragma unroll
        for (int kc = 0; kc < 8; ++kc)
            afr[g][kc] = *(const bf16x8*)(WA + (((wv * 4 + g) * 8 + kc) * 64 + lane) * 8);

    // own seq id + packed words (8 bits each) in a 128-bit shift register
    const int slot = widx * WGSEQ + lane31;
    const int live = slot < cnt;
    const int sid  = live ? perm[b * BINCAP + slot] : 0;
    unsigned long long u0, u1;
    {
        const i32x4* wp = (const i32x4*)(word_ids + sid * SEQL);
        i32x4 a = wp[0], b4 = wp[1], c4 = wp[2], d4 = wp[3];
        unsigned lo0 = (unsigned)(a.x  | (a.y  << 8) | (a.z  << 16) | (a.w  << 24));
        unsigned hi0 = (unsigned)(b4.x | (b4.y << 8) | (b4.z << 16) | (b4.w << 24));
        unsigned lo1 = (unsigned)(c4.x | (c4.y << 8) | (c4.z << 16) | (c4.w << 24));
        unsigned hi1 = (unsigned)(d4.x | (d4.y << 8) | (d4.z << 16) | (d4.w << 24));
        u0 = ((unsigned long long)hi0 << 32) | lo0;
        u1 = ((unsigned long long)hi1 << 32) | lo1;
    }
    __syncthreads();                   // table staged (vmcnt drained by barrier)

    f32x4 cq[4] = {{0,0,0,0},{0,0,0,0},{0,0,0,0},{0,0,0,0}};
    const int      rdo_b = lane31 * 256;           // byte offset of own h row
    const unsigned xv    = (unsigned)((lane31 & 7) << 4);
    const int      jbase = wv * 32 + 4 * hl;
    const int      ccb   = wv * 4 + hl * 2;        // chunk base (g adds g*16)

#pragma unroll 1
    for (int t = 0; t < ml; ++t) {
        const int w = (int)(u0 & 63);
        u0 = (u0 >> 8) | (u1 << 56); u1 >>= 8;

        // acc init = gate pre-activations P[w] from static LDS table
        AccU acc[4];
        {
            const char*    rowp = (const char*)ptab + (w << 10);
            const unsigned wx   = (unsigned)((w & 7) << 4);
#pragma unroll
            for (int g = 0; g < 4; ++g)
#pragma unroll
                for (int s = 0; s < 2; ++s) {
                    const unsigned off = ((unsigned)((g * 16 + ccb + s) << 4)) ^ wx;
                    f16x8 hv = *(const f16x8*)(rowp + off);
#pragma unroll
                    for (int k = 0; k < 8; ++k)
                        acc[g].f[s * 8 + k] = (float)hv[k];
                }
        }

        if (t > 0) {   // recurrent GEMM (t=0 has h=0)
            const char* hr = (const char*)hbuf[t & 1];
            bf16x8 bfv[8];
#pragma unroll
            for (int kc = 0; kc < 8; ++kc)
                bfv[kc] = *(const bf16x8*)(hr + rdo_b +
                              (((unsigned)(kc * 32 + hl * 16)) ^ xv));
#pragma unroll
            for (int kc = 0; kc < 8; ++kc) {
                const bf16x8 bb = bfv[kc];
#pragma unroll
                for (int g = 0; g < 4; ++g)
                    acc[g].v = __builtin_amdgcn_mfma_f32_32x32x16_bf16(
                        afr[g][kc], bb, acc[g].v, 0, 0, 0);
            }
        }

        const int wr = (t < ml - 1);
        char* hw = (char*)hbuf[(t + 1) & 1];
#pragma unroll
        for (int q = 0; q < 4; ++q) {
            float hv4[4];
#pragma unroll
            for (int d = 0; d < 4; ++d) {
                const int r = q * 4 + d;
                // shared-rcp gate math (exact refactor):
                // i*tanh(g) = (eg-1) / ((1+ei)(1+eg)); f = 1/(1+ef)
                float ei = __builtin_amdgcn_exp2f(acc[0].f[r] * -1.44269504f);
                float ef = __builtin_amdgcn_exp2f(acc[1].f[r] * -1.44269504f);
                float eg = __builtin_amdgcn_exp2f(acc[2].f[r] *  2.88539008f);
                float fg  = __builtin_amdgcn_rcpf(1.f + ef);
                float igg = (eg - 1.f) *
                            __builtin_amdgcn_rcpf((1.f + ei) * (1.f + eg));
                float cn = cq[q][d] * fg + igg;
                cq[q][d] = cn;
                if (wr) {
                    // o*tanh(c) = (ec-1) / ((1+eo)(1+ec))
                    float eo = __builtin_amdgcn_exp2f(acc[3].f[r] * -1.44269504f);
                    float ec = __builtin_amdgcn_exp2f(cn * 2.88539008f);
                    hv4[d] = (ec - 1.f) *
                             __builtin_amdgcn_rcpf((1.f + eo) * (1.f + ec));
                }
            }
            if (wr) {
                unsigned int plo_, phi_;
                asm("v_cvt_pk_bf16_f32 %0, %1, %2"
                    : "=v"(plo_) : "v"(hv4[0]), "v"(hv4[1]));
                asm("v_cvt_pk_bf16_f32 %0, %1, %2"
                    : "=v"(phi_) : "v"(hv4[2]), "v"(hv4[3]));
                unsigned long long pu_ =
                    ((unsigned long long)phi_ << 32) | plo_;
                *(unsigned long long*)(hw + rdo_b +
                    (((unsigned)(wv * 64 + q * 16)) ^ xv) + hl * 8) = pu_;
            }
        }
        if (wr) __syncthreads();       // h(t+1) visible; single barrier/step
    }

    // final cell state -> original seq order (dwordx4 stores)
    if (live) {
#pragma unroll
        for (int q = 0; q < 4; ++q)
            *(f32x4*)(c_out + sid * HDIM + jbase + 8 * q) = cq[q];
    }
}

// ---------------------------------------------------------------------------
// Per-batch epilogue: gram -> cosine -> conv1 -> conv2 -> scorer -> sigmoid.
// ---------------------------------------------------------------------------
__global__ __launch_bounds__(256) void epilogue(
    const float* __restrict__ c_ws,
    const float* __restrict__ conv1_w, const float* __restrict__ conv1_b,
    const float* __restrict__ conv2_w, const float* __restrict__ conv2_b,
    const float* __restrict__ scorer_w, const float* __restrict__ scorer_b,
    float* __restrict__ out)
{
    __shared__ __align__(16) float reps[8 * NWRD * HDIM];   // 16KB
    __shared__ float gram_s[8 * 16];

    const int tid = threadIdx.x;
    const int b0  = blockIdx.x * 8;

    for (int i = tid; i < 8 * NWRD * HDIM; i += 256)
        reps[i] = c_ws[b0 * NWRD * HDIM + i];
    __syncthreads();

    const int bt  = tid >> 5;   // 0..7
    const int sub = tid & 31;

    float dval = 0.f;
    if (sub < 16) {
        int i = sub >> 2, j = sub & 3;
        const f32x4* ci = (const f32x4*)(reps + (bt * 4 + i) * HDIM);
        const f32x4* cj = (const f32x4*)(reps + (bt * 4 + j) * HDIM);
        f32x4 s4 = {0.f, 0.f, 0.f, 0.f};
        for (int k = 0; k < HDIM / 4; ++k) s4 += ci[k] * cj[k];
        dval = s4.x + s4.y + s4.z + s4.w;
        gram_s[bt * 16 + sub] = dval;
    }
    __syncthreads();
    float cosv = 0.f;
    if (sub < 16) {
        int i = sub >> 2, j = sub & 3;
        float di = gram_s[bt * 16 + i * 4 + i];
        float dj = gram_s[bt * 16 + j * 4 + j];
        cosv = __fdividef(dval, sqrtf(di * dj));
    }
    __syncthreads();
    if (sub < 16) gram_s[bt * 16 + sub] = cosv;
    __syncthreads();

    if (sub == 0) {
        float img[4][4];
#pragma unroll
        for (int i = 0; i < 4; ++i)
#pragma unroll
            for (int j = 0; j < 4; ++j) img[i][j] = gram_s[bt * 16 + i * 4 + j];

        float o1[4][3][3];
#pragma unroll
        for (int ch = 0; ch < 4; ++ch) {
            float w00 = conv1_w[ch*4+0], w01 = conv1_w[ch*4+1];
            float w10 = conv1_w[ch*4+2], w11 = conv1_w[ch*4+3];
            float bb  = conv1_b[ch];
#pragma unroll
            for (int y = 0; y < 3; ++y)
#pragma unroll
                for (int x = 0; x < 3; ++x) {
                    float s = bb + w00*img[y][x]   + w01*img[y][x+1]
                                 + w10*img[y+1][x] + w11*img[y+1][x+1];
                    o1[ch][y][x] = s > 0.f ? s : 0.f;
                }
        }
        float sc = scorer_b[0];
#pragma unroll
        for (int oc = 0; oc < 8; ++oc) {
            float bb = conv2_b[oc];
#pragma unroll
            for (int y = 0; y < 2; ++y)
#pragma unroll
                for (int x = 0; x < 2; ++x) {
                    float s = bb;
#pragma unroll
                    for (int ic = 0; ic < 4; ++ic) {
                        const float* w = conv2_w + oc * 16 + ic * 4;
                        s += w[0]*o1[ic][y][x]   + w[1]*o1[ic][y][x+1]
                           + w[2]*o1[ic][y+1][x] + w[3]*o1[ic][y+1][x+1];
                    }
                    float rl = s > 0.f ? s : 0.f;
                    sc += rl * scorer_w[oc * 4 + y * 2 + x];
                }
        }
        out[blockIdx.x * 8 + bt] = sigm(sc);
    }
}

extern "C" void kernel_launch(void* const* d_in, const int* in_sizes, int n_in,
                              void* d_out, int out_size, void* d_ws, size_t ws_size,
                              hipStream_t stream)
{
    const int*   word_ids = (const int*)d_in[0];
    const int*   lengths  = (const int*)d_in[1];
    const float* emb      = (const float*)d_in[2];
    const float* W_ih     = (const float*)d_in[3];
    const float* W_hh     = (const float*)d_in[4];
    const float* b_ih     = (const float*)d_in[5];
    const float* b_hh     = (const float*)d_in[6];
    const float* conv1_w  = (const float*)d_in[7];
    const float* conv1_b  = (const float*)d_in[8];
    const float* conv2_w  = (const float*)d_in[9];
    const float* conv2_b  = (const float*)d_in[10];
    const float* scorer_w = (const float*)d_in[11];
    const float* scorer_b = (const float*)d_in[12];
    float* out = (float*)d_out;

    // workspace layout
    char* ws = (char*)d_ws;
    unsigned short* P2H  = (unsigned short*)(ws + 0);         // 64 KB (f16 table)
    unsigned short* WA   = (unsigned short*)(ws + (128<<10)); // 128 KB
    int*            perm = (int*)(ws + (256<<10));            // 16*2560*4 = 160 KB
    int*            gh   = (int*)(ws + (416<<10));            // 64 B bin cursors
    float*          c_ws = (float*)(ws + (512<<10));          // 16 MB

    hipMemsetAsync(gh, 0, 16 * sizeof(int), stream);
    prep4   <<<512,   256, 0, stream>>>(emb, W_ih, b_ih, b_hh, W_hh, lengths,
                                        P2H, WA, perm, gh);
    lstm4   <<<NUNITS, 256, 0, stream>>>(word_ids, perm, gh, P2H, WA, c_ws);
    epilogue<<<BSZ / 8, 256, 0, stream>>>(c_ws, conv1_w, conv1_b, conv2_w, conv2_b,
                                          scorer_w, scorer_b, out);
}